// Round 1
// baseline (163.466 us; speedup 1.0000x reference)
//
#include <hip/hip_runtime.h>

// CapsNet dynamic routing, fully fused.
// x: [128, 1152, 8] fp32, w: [1152, 10, 8, 16] fp32 -> v: [128, 10, 16] fp32
// One block per (j, b) pair; u_hat[b,:,j,:] lives entirely in registers.

#define NB 128
#define NI 1152
#define NJ 10
#define ID 8
#define OD 16
#define NTHREADS 384      // 6 waves; 1152 / 384 = 3 i-rows per thread
#define IPT 3
#define NWAVES (NTHREADS / 64)

__global__ __launch_bounds__(NTHREADS) void caps_route_kernel(
    const float* __restrict__ x, const float* __restrict__ w,
    float* __restrict__ out)
{
    const int t = threadIdx.x;
    const int b = blockIdx.x & (NB - 1);   // batch
    const int j = blockIdx.x >> 7;         // output capsule (j-major grid)

    // ---- Compute u[k][m] = u_hat[b, i_k, j, m],  i_k = t + k*NTHREADS ----
    float u[IPT][OD];
    #pragma unroll
    for (int k = 0; k < IPT; ++k) {
        const int i = t + k * NTHREADS;
        // x[b, i, 0..7] : 32B-aligned, coalesced across the wave
        const float* xp = x + ((size_t)b * NI + i) * ID;
        float xv[ID];
        {
            const float4 x0 = *(const float4*)(xp);
            const float4 x1 = *(const float4*)(xp + 4);
            xv[0]=x0.x; xv[1]=x0.y; xv[2]=x0.z; xv[3]=x0.w;
            xv[4]=x1.x; xv[5]=x1.y; xv[6]=x1.z; xv[7]=x1.w;
        }
        // w[i, j, :, :] : 128 consecutive floats
        const float* wp = w + (size_t)i * (NJ * ID * OD) + (size_t)j * (ID * OD);
        #pragma unroll
        for (int m = 0; m < OD; ++m) u[k][m] = 0.0f;
        #pragma unroll
        for (int n = 0; n < ID; ++n) {
            float wr[OD];
            *(float4*)(wr + 0)  = *(const float4*)(wp + n * OD + 0);
            *(float4*)(wr + 4)  = *(const float4*)(wp + n * OD + 4);
            *(float4*)(wr + 8)  = *(const float4*)(wp + n * OD + 8);
            *(float4*)(wr + 12) = *(const float4*)(wp + n * OD + 12);
            const float xn = xv[n];
            #pragma unroll
            for (int m = 0; m < OD; ++m) u[k][m] = fmaf(xn, wr[m], u[k][m]);
        }
    }

    // ---- Dynamic routing: 3 iterations, all in registers + 17-float reduce ----
    __shared__ float red[NWAVES][OD + 1];

    float logit[IPT] = {0.0f, 0.0f, 0.0f};
    float v[OD];

    for (int iter = 0; iter < 3; ++iter) {
        // Deferred-normalization softmax: acc[0..15] = sum_i e^{b_i} u_i,
        // acc[16] = sum_i e^{b_i}.  (iter 0: b=0 -> uniform, same path.)
        float acc[OD + 1];
        #pragma unroll
        for (int q = 0; q <= OD; ++q) acc[q] = 0.0f;
        #pragma unroll
        for (int k = 0; k < IPT; ++k) {
            const float c = __expf(logit[k]);
            acc[OD] += c;
            #pragma unroll
            for (int m = 0; m < OD; ++m) acc[m] = fmaf(c, u[k][m], acc[m]);
        }
        // wave-level butterfly reduce (64 lanes)
        #pragma unroll
        for (int off = 32; off > 0; off >>= 1) {
            #pragma unroll
            for (int q = 0; q <= OD; ++q)
                acc[q] += __shfl_down(acc[q], off, 64);
        }
        const int wave = t >> 6;
        const int lane = t & 63;
        if (iter != 0) __syncthreads();   // red[] reads of prev iter done
        if (lane == 0) {
            #pragma unroll
            for (int q = 0; q <= OD; ++q) red[wave][q] = acc[q];
        }
        __syncthreads();
        // every thread forms the block total (broadcast LDS reads)
        float tot[OD + 1];
        #pragma unroll
        for (int q = 0; q <= OD; ++q) {
            float sq = red[0][q];
            #pragma unroll
            for (int wv = 1; wv < NWAVES; ++wv) sq += red[wv][q];
            tot[q] = sq;
        }
        const float inv_den = 1.0f / tot[OD];
        float s2 = 0.0f;
        float sv[OD];
        #pragma unroll
        for (int m = 0; m < OD; ++m) {
            sv[m] = tot[m] * inv_den;
            s2 = fmaf(sv[m], sv[m], s2);
        }
        // squash: v = (s2/(1+s2)) * s / sqrt(s2 + 1e-8)
        const float scale = (s2 / (1.0f + s2)) / sqrtf(s2 + 1e-8f);
        #pragma unroll
        for (int m = 0; m < OD; ++m) v[m] = scale * sv[m];

        if (iter < 2) {
            // b += v . u_i   (agreement update)
            #pragma unroll
            for (int k = 0; k < IPT; ++k) {
                float a = 0.0f;
                #pragma unroll
                for (int m = 0; m < OD; ++m) a = fmaf(v[m], u[k][m], a);
                logit[k] += a;
            }
        }
    }

    // ---- Write v[b, j, :] ----
    if (t < OD) out[((size_t)b * NJ + j) * OD + t] = v[t];
}

extern "C" void kernel_launch(void* const* d_in, const int* in_sizes, int n_in,
                              void* d_out, int out_size, void* d_ws, size_t ws_size,
                              hipStream_t stream) {
    // d_in order: nums_caps (scalar), out_caps (scalar), x, w
    const float* x = (const float*)d_in[2];
    const float* w = (const float*)d_in[3];
    float* out = (float*)d_out;
    dim3 grid(NB * NJ);   // 1280 blocks, j-major (blockIdx = j*128 + b)
    dim3 block(NTHREADS);
    hipLaunchKernelGGL(caps_route_kernel, grid, block, 0, stream, x, w, out);
}

// Round 2
// 111.960 us; speedup vs baseline: 1.4600x; 1.4600x over previous
//
#include <hip/hip_runtime.h>

// CapsNet dynamic routing, two-phase.
// x: [128, 1152, 8] fp32, w: [1152, 10, 8, 16] fp32 -> v: [128, 10, 16] fp32
// Phase 1: u_hat[b][j][i][m] into d_ws (w read exactly once).
// Phase 2: routing per (b,j) with u_hat in registers via coalesced streaming loads.

#define NB 128
#define NI 1152
#define NJ 10
#define ID 8
#define OD 16

// ---------------- Phase 1: u_hat = einsum('ijnm,bin->b j i m') ----------------
// Block handles i0 = 2*blockIdx (two i's => 128 B contiguous stores).
// 320 threads: j = t>>5 (0..9), bs = t&31, each thread does b = bs + 32k, k=0..3.
#define P1_THREADS 320

__global__ __launch_bounds__(P1_THREADS) void uhat_kernel(
    const float* __restrict__ x, const float* __restrict__ w,
    float* __restrict__ uhat)
{
    const int t  = threadIdx.x;
    const int i0 = blockIdx.x * 2;
    const int j  = t >> 5;
    const int bs = t & 31;

    float acc[2][4][16];
    #pragma unroll
    for (int i2 = 0; i2 < 2; ++i2) {
        const int i = i0 + i2;
        // x rows for this thread's 4 batches
        float xv[4][ID];
        #pragma unroll
        for (int k = 0; k < 4; ++k) {
            const float* xp = x + ((size_t)(bs + 32 * k) * NI + i) * ID;
            const float4 a0 = *(const float4*)xp;
            const float4 a1 = *(const float4*)(xp + 4);
            xv[k][0]=a0.x; xv[k][1]=a0.y; xv[k][2]=a0.z; xv[k][3]=a0.w;
            xv[k][4]=a1.x; xv[k][5]=a1.y; xv[k][6]=a1.z; xv[k][7]=a1.w;
        }
        #pragma unroll
        for (int k = 0; k < 4; ++k)
            #pragma unroll
            for (int m = 0; m < OD; ++m) acc[i2][k][m] = 0.0f;

        // w[i][j][n][m]: 512 B contiguous; broadcast across the 32-lane j-group (L1-served)
        const float* wp = w + ((size_t)i * NJ + j) * (ID * OD);
        #pragma unroll
        for (int n = 0; n < ID; ++n) {
            float wr[OD];
            *(float4*)(wr + 0)  = *(const float4*)(wp + n * OD + 0);
            *(float4*)(wr + 4)  = *(const float4*)(wp + n * OD + 4);
            *(float4*)(wr + 8)  = *(const float4*)(wp + n * OD + 8);
            *(float4*)(wr + 12) = *(const float4*)(wp + n * OD + 12);
            #pragma unroll
            for (int k = 0; k < 4; ++k) {
                const float xn = xv[k][n];
                #pragma unroll
                for (int m = 0; m < OD; ++m)
                    acc[i2][k][m] = fmaf(xn, wr[m], acc[i2][k][m]);
            }
        }
    }

    // Store: per k, 128 B contiguous ([i0][m0..15][i0+1][m0..15]) — full cache lines.
    #pragma unroll
    for (int k = 0; k < 4; ++k) {
        const int b = bs + 32 * k;
        float* up = uhat + (((size_t)b * NJ + j) * NI + i0) * OD;
        #pragma unroll
        for (int i2 = 0; i2 < 2; ++i2) {
            #pragma unroll
            for (int q = 0; q < 4; ++q) {
                float4 s;
                s.x = acc[i2][k][q * 4 + 0];
                s.y = acc[i2][k][q * 4 + 1];
                s.z = acc[i2][k][q * 4 + 2];
                s.w = acc[i2][k][q * 4 + 3];
                *(float4*)(up + i2 * OD + q * 4) = s;
            }
        }
    }
}

// ---------------- Phase 2: routing, u_hat streamed into registers ----------------
#define NTHREADS 384
#define IPT 3
#define NWAVES (NTHREADS / 64)

__device__ __forceinline__ void route_core(float u[IPT][OD], int t, int b, int j,
                                           float* __restrict__ out)
{
    __shared__ float red[NWAVES][OD + 1];
    float logit[IPT] = {0.0f, 0.0f, 0.0f};
    float v[OD];

    for (int iter = 0; iter < 3; ++iter) {
        float acc[OD + 1];
        #pragma unroll
        for (int q = 0; q <= OD; ++q) acc[q] = 0.0f;
        #pragma unroll
        for (int k = 0; k < IPT; ++k) {
            const float c = __expf(logit[k]);
            acc[OD] += c;
            #pragma unroll
            for (int m = 0; m < OD; ++m) acc[m] = fmaf(c, u[k][m], acc[m]);
        }
        #pragma unroll
        for (int off = 32; off > 0; off >>= 1) {
            #pragma unroll
            for (int q = 0; q <= OD; ++q)
                acc[q] += __shfl_down(acc[q], off, 64);
        }
        const int wave = t >> 6;
        const int lane = t & 63;
        if (iter != 0) __syncthreads();
        if (lane == 0) {
            #pragma unroll
            for (int q = 0; q <= OD; ++q) red[wave][q] = acc[q];
        }
        __syncthreads();
        float tot[OD + 1];
        #pragma unroll
        for (int q = 0; q <= OD; ++q) {
            float sq = red[0][q];
            #pragma unroll
            for (int wv = 1; wv < NWAVES; ++wv) sq += red[wv][q];
            tot[q] = sq;
        }
        const float inv_den = 1.0f / tot[OD];
        float s2 = 0.0f;
        float sv[OD];
        #pragma unroll
        for (int m = 0; m < OD; ++m) {
            sv[m] = tot[m] * inv_den;
            s2 = fmaf(sv[m], sv[m], s2);
        }
        const float scale = (s2 / (1.0f + s2)) / sqrtf(s2 + 1e-8f);
        #pragma unroll
        for (int m = 0; m < OD; ++m) v[m] = scale * sv[m];

        if (iter < 2) {
            #pragma unroll
            for (int k = 0; k < IPT; ++k) {
                float a = 0.0f;
                #pragma unroll
                for (int m = 0; m < OD; ++m) a = fmaf(v[m], u[k][m], a);
                logit[k] += a;
            }
        }
    }
    if (t < OD) out[((size_t)b * NJ + j) * OD + t] = v[t];
}

__global__ __launch_bounds__(NTHREADS) void route_kernel(
    const float* __restrict__ uhat, float* __restrict__ out)
{
    const int t = threadIdx.x;
    const int b = blockIdx.x & (NB - 1);
    const int j = blockIdx.x >> 7;

    const float* up = uhat + ((size_t)b * NJ + j) * NI * OD;
    float u[IPT][OD];
    #pragma unroll
    for (int k = 0; k < IPT; ++k) {
        const float* p = up + (size_t)(t + k * NTHREADS) * OD;
        const float4 a0 = *(const float4*)(p + 0);
        const float4 a1 = *(const float4*)(p + 4);
        const float4 a2 = *(const float4*)(p + 8);
        const float4 a3 = *(const float4*)(p + 12);
        u[k][0]=a0.x; u[k][1]=a0.y; u[k][2]=a0.z; u[k][3]=a0.w;
        u[k][4]=a1.x; u[k][5]=a1.y; u[k][6]=a1.z; u[k][7]=a1.w;
        u[k][8]=a2.x; u[k][9]=a2.y; u[k][10]=a2.z; u[k][11]=a2.w;
        u[k][12]=a3.x; u[k][13]=a3.y; u[k][14]=a3.z; u[k][15]=a3.w;
    }
    route_core(u, t, b, j, out);
}

// ---------------- Fallback: original fused kernel (if d_ws too small) ----------------
__global__ __launch_bounds__(NTHREADS) void caps_route_kernel(
    const float* __restrict__ x, const float* __restrict__ w,
    float* __restrict__ out)
{
    const int t = threadIdx.x;
    const int b = blockIdx.x & (NB - 1);
    const int j = blockIdx.x >> 7;

    float u[IPT][OD];
    #pragma unroll
    for (int k = 0; k < IPT; ++k) {
        const int i = t + k * NTHREADS;
        const float* xp = x + ((size_t)b * NI + i) * ID;
        float xv[ID];
        {
            const float4 x0 = *(const float4*)(xp);
            const float4 x1 = *(const float4*)(xp + 4);
            xv[0]=x0.x; xv[1]=x0.y; xv[2]=x0.z; xv[3]=x0.w;
            xv[4]=x1.x; xv[5]=x1.y; xv[6]=x1.z; xv[7]=x1.w;
        }
        const float* wp = w + (size_t)i * (NJ * ID * OD) + (size_t)j * (ID * OD);
        #pragma unroll
        for (int m = 0; m < OD; ++m) u[k][m] = 0.0f;
        #pragma unroll
        for (int n = 0; n < ID; ++n) {
            float wr[OD];
            *(float4*)(wr + 0)  = *(const float4*)(wp + n * OD + 0);
            *(float4*)(wr + 4)  = *(const float4*)(wp + n * OD + 4);
            *(float4*)(wr + 8)  = *(const float4*)(wp + n * OD + 8);
            *(float4*)(wr + 12) = *(const float4*)(wp + n * OD + 12);
            const float xn = xv[n];
            #pragma unroll
            for (int m = 0; m < OD; ++m) u[k][m] = fmaf(xn, wr[m], u[k][m]);
        }
    }
    route_core(u, t, b, j, out);
}

extern "C" void kernel_launch(void* const* d_in, const int* in_sizes, int n_in,
                              void* d_out, int out_size, void* d_ws, size_t ws_size,
                              hipStream_t stream) {
    const float* x = (const float*)d_in[2];
    const float* w = (const float*)d_in[3];
    float* out = (float*)d_out;

    const size_t UHAT_BYTES = (size_t)NB * NJ * NI * OD * sizeof(float); // ~94.4 MB

    if (ws_size >= UHAT_BYTES) {
        float* uhat = (float*)d_ws;
        hipLaunchKernelGGL(uhat_kernel, dim3(NI / 2), dim3(P1_THREADS), 0, stream,
                           x, w, uhat);
        hipLaunchKernelGGL(route_kernel, dim3(NB * NJ), dim3(NTHREADS), 0, stream,
                           uhat, out);
    } else {
        hipLaunchKernelGGL(caps_route_kernel, dim3(NB * NJ), dim3(NTHREADS), 0, stream,
                           x, w, out);
    }
}

// Round 3
// 85.834 us; speedup vs baseline: 1.9045x; 1.3044x over previous
//
#include <hip/hip_runtime.h>
#include <hip/hip_fp16.h>

// CapsNet dynamic routing, two-phase, fp16 u_hat.
// x: [128, 1152, 8] fp32, w: [1152, 10, 8, 16] fp32 -> v: [128, 10, 16] fp32
// Phase 1: u_hat[b][j][i][m] (fp16) into d_ws; grid 18x8x10, lane<->i.
// Phase 2: routing per (b,j), u_hat streamed to registers.

#define NB 128
#define NI 1152
#define NJ 10
#define ID 8
#define OD 16

// ---------------- Phase 1: u_hat = einsum('ijnm,bin->b j i m'), fp16 out ----------------
// Block: 256 threads = 64 i-lanes x 4 waves; each wave handles 4 b's.
// Grid: (NI/64, NB/16, NJ) = (18, 8, 10) = 1440 blocks.
__global__ __launch_bounds__(256) void uhat_fp16_kernel(
    const float* __restrict__ x, const float* __restrict__ w,
    __half* __restrict__ uhat)
{
    const int t  = threadIdx.x;
    const int il = t & 63;
    const int wv = t >> 6;
    const int i  = blockIdx.x * 64 + il;
    const int j  = blockIdx.z;
    const int b0 = blockIdx.y * 16 + wv * 4;

    // x[b][i][0..7] for this thread's 4 batches (32 B/lane, wave-contiguous)
    float xv[4][ID];
    #pragma unroll
    for (int kb = 0; kb < 4; ++kb) {
        const float* xp = x + ((size_t)(b0 + kb) * NI + i) * ID;
        const float4 a0 = *(const float4*)xp;
        const float4 a1 = *(const float4*)(xp + 4);
        xv[kb][0]=a0.x; xv[kb][1]=a0.y; xv[kb][2]=a0.z; xv[kb][3]=a0.w;
        xv[kb][4]=a1.x; xv[kb][5]=a1.y; xv[kb][6]=a1.z; xv[kb][7]=a1.w;
    }

    const float* wp = w + ((size_t)i * NJ + j) * (ID * OD);

    float acc[4][OD];
    #pragma unroll
    for (int kb = 0; kb < 4; ++kb)
        #pragma unroll
        for (int m = 0; m < OD; ++m) acc[kb][m] = 0.0f;

    // n in pairs: load 2 w-rows (32 floats, 128 B/lane contiguous), FMA into 4 b's
    #pragma unroll
    for (int nc = 0; nc < 4; ++nc) {
        float wr[32];
        #pragma unroll
        for (int q = 0; q < 8; ++q)
            *(float4*)(wr + 4 * q) = *(const float4*)(wp + nc * 32 + 4 * q);
        #pragma unroll
        for (int kb = 0; kb < 4; ++kb) {
            const float xa = xv[kb][2 * nc];
            const float xb = xv[kb][2 * nc + 1];
            #pragma unroll
            for (int m = 0; m < OD; ++m)
                acc[kb][m] = fmaf(xb, wr[16 + m], fmaf(xa, wr[m], acc[kb][m]));
        }
    }

    // store fp16: 32 B/lane contiguous, wave writes 2 KB contiguous per kb
    #pragma unroll
    for (int kb = 0; kb < 4; ++kb) {
        const int b = b0 + kb;
        __half h[OD];
        #pragma unroll
        for (int m = 0; m < OD; ++m) h[m] = __float2half(acc[kb][m]);
        __half* up = uhat + (((size_t)b * NJ + j) * NI + i) * OD;
        *(float4*)(up)     = *(const float4*)(h);
        *(float4*)(up + 8) = *(const float4*)(h + 8);
    }
}

// ---------------- Phase 2: routing ----------------
#define NTHREADS 384
#define IPT 3
#define NWAVES (NTHREADS / 64)

__device__ __forceinline__ void route_core(float u[IPT][OD], int t, int b, int j,
                                           float* __restrict__ out)
{
    __shared__ float red[NWAVES][OD + 1];
    float logit[IPT] = {0.0f, 0.0f, 0.0f};
    float v[OD];

    for (int iter = 0; iter < 3; ++iter) {
        float acc[OD + 1];
        #pragma unroll
        for (int q = 0; q <= OD; ++q) acc[q] = 0.0f;
        #pragma unroll
        for (int k = 0; k < IPT; ++k) {
            const float c = __expf(logit[k]);
            acc[OD] += c;
            #pragma unroll
            for (int m = 0; m < OD; ++m) acc[m] = fmaf(c, u[k][m], acc[m]);
        }
        #pragma unroll
        for (int off = 32; off > 0; off >>= 1) {
            #pragma unroll
            for (int q = 0; q <= OD; ++q)
                acc[q] += __shfl_down(acc[q], off, 64);
        }
        const int wave = t >> 6;
        const int lane = t & 63;
        if (iter != 0) __syncthreads();
        if (lane == 0) {
            #pragma unroll
            for (int q = 0; q <= OD; ++q) red[wave][q] = acc[q];
        }
        __syncthreads();
        float tot[OD + 1];
        #pragma unroll
        for (int q = 0; q <= OD; ++q) {
            float sq = red[0][q];
            #pragma unroll
            for (int wv = 1; wv < NWAVES; ++wv) sq += red[wv][q];
            tot[q] = sq;
        }
        const float inv_den = 1.0f / tot[OD];
        float s2 = 0.0f;
        float sv[OD];
        #pragma unroll
        for (int m = 0; m < OD; ++m) {
            sv[m] = tot[m] * inv_den;
            s2 = fmaf(sv[m], sv[m], s2);
        }
        const float scale = (s2 / (1.0f + s2)) / sqrtf(s2 + 1e-8f);
        #pragma unroll
        for (int m = 0; m < OD; ++m) v[m] = scale * sv[m];

        if (iter < 2) {
            #pragma unroll
            for (int k = 0; k < IPT; ++k) {
                float a = 0.0f;
                #pragma unroll
                for (int m = 0; m < OD; ++m) a = fmaf(v[m], u[k][m], a);
                logit[k] += a;
            }
        }
    }
    if (t < OD) out[((size_t)b * NJ + j) * OD + t] = v[t];
}

__global__ __launch_bounds__(NTHREADS) void route_fp16_kernel(
    const __half* __restrict__ uhat, float* __restrict__ out)
{
    const int t = threadIdx.x;
    const int b = blockIdx.x & (NB - 1);
    const int j = blockIdx.x >> 7;

    const __half* up = uhat + ((size_t)b * NJ + j) * NI * OD;
    float u[IPT][OD];
    #pragma unroll
    for (int k = 0; k < IPT; ++k) {
        const __half* p = up + (size_t)(t + k * NTHREADS) * OD;
        __half h[OD];
        *(float4*)(h)     = *(const float4*)(p);
        *(float4*)(h + 8) = *(const float4*)(p + 8);
        #pragma unroll
        for (int m = 0; m < OD; ++m) u[k][m] = __half2float(h[m]);
    }
    route_core(u, t, b, j, out);
}

// ---------------- Fallback: fully fused fp32 (if d_ws too small) ----------------
__global__ __launch_bounds__(NTHREADS) void caps_route_kernel(
    const float* __restrict__ x, const float* __restrict__ w,
    float* __restrict__ out)
{
    const int t = threadIdx.x;
    const int b = blockIdx.x & (NB - 1);
    const int j = blockIdx.x >> 7;

    float u[IPT][OD];
    #pragma unroll
    for (int k = 0; k < IPT; ++k) {
        const int i = t + k * NTHREADS;
        const float* xp = x + ((size_t)b * NI + i) * ID;
        float xv[ID];
        {
            const float4 x0 = *(const float4*)(xp);
            const float4 x1 = *(const float4*)(xp + 4);
            xv[0]=x0.x; xv[1]=x0.y; xv[2]=x0.z; xv[3]=x0.w;
            xv[4]=x1.x; xv[5]=x1.y; xv[6]=x1.z; xv[7]=x1.w;
        }
        const float* wp = w + (size_t)i * (NJ * ID * OD) + (size_t)j * (ID * OD);
        #pragma unroll
        for (int m = 0; m < OD; ++m) u[k][m] = 0.0f;
        #pragma unroll
        for (int n = 0; n < ID; ++n) {
            float wr[OD];
            *(float4*)(wr + 0)  = *(const float4*)(wp + n * OD + 0);
            *(float4*)(wr + 4)  = *(const float4*)(wp + n * OD + 4);
            *(float4*)(wr + 8)  = *(const float4*)(wp + n * OD + 8);
            *(float4*)(wr + 12) = *(const float4*)(wp + n * OD + 12);
            const float xn = xv[n];
            #pragma unroll
            for (int m = 0; m < OD; ++m) u[k][m] = fmaf(xn, wr[m], u[k][m]);
        }
    }
    route_core(u, t, b, j, out);
}

extern "C" void kernel_launch(void* const* d_in, const int* in_sizes, int n_in,
                              void* d_out, int out_size, void* d_ws, size_t ws_size,
                              hipStream_t stream) {
    const float* x = (const float*)d_in[2];
    const float* w = (const float*)d_in[3];
    float* out = (float*)d_out;

    const size_t UHAT_BYTES = (size_t)NB * NJ * NI * OD * sizeof(__half); // ~47.2 MB

    if (ws_size >= UHAT_BYTES) {
        __half* uhat = (__half*)d_ws;
        hipLaunchKernelGGL(uhat_fp16_kernel, dim3(NI / 64, NB / 16, NJ), dim3(256),
                           0, stream, x, w, uhat);
        hipLaunchKernelGGL(route_fp16_kernel, dim3(NB * NJ), dim3(NTHREADS),
                           0, stream, uhat, out);
    } else {
        hipLaunchKernelGGL(caps_route_kernel, dim3(NB * NJ), dim3(NTHREADS),
                           0, stream, x, w, out);
    }
}

// Round 4
// 39.386 us; speedup vs baseline: 4.1503x; 2.1793x over previous
//
#include <hip/hip_runtime.h>
#include <hip/hip_fp16.h>

// CapsNet dynamic routing, two-phase, fp16 u_hat, DPP reductions.
// x: [128, 1152, 8] fp32, w: [1152, 10, 8, 16] fp32 -> v: [128, 10, 16] fp32

#define NB 128
#define NI 1152
#define NJ 10
#define ID 8
#define OD 16

// ---- DPP wave-64 sum (rocPRIM pattern): full sum lands in lane 63 ----
template<int ctrl, int rmask, int bmask>
__device__ __forceinline__ float dpp_add(float x) {
    int y = __builtin_amdgcn_update_dpp(0, __builtin_bit_cast(int, x),
                                        ctrl, rmask, bmask, false);
    return x + __builtin_bit_cast(float, y);
}
__device__ __forceinline__ float wave_sum63(float x) {
    x = dpp_add<0x111, 0xf, 0xf>(x);  // row_shr:1
    x = dpp_add<0x112, 0xf, 0xf>(x);  // row_shr:2
    x = dpp_add<0x114, 0xf, 0xe>(x);  // row_shr:4
    x = dpp_add<0x118, 0xf, 0xc>(x);  // row_shr:8
    x = dpp_add<0x142, 0xa, 0xf>(x);  // row_bcast:15
    x = dpp_add<0x143, 0xc, 0xf>(x);  // row_bcast:31
    return x;                          // lane 63 = sum of all 64 lanes
}

// ---------------- Phase 1: u_hat[b][j][i][m] (fp16) ----------------
// Grid (18, 8, 10): i-tile 64, b-tile 16, j.  256 threads.
// Wave = 16 i-groups x 4 m-quarter lanes: w loads are 64B-contiguous per
// 4-lane group; x staged in LDS (stride-10 pad => conflict-free b64 reads);
// stores are 512B-contiguous per wave.
__global__ __launch_bounds__(256) void uhat_kernel(
    const float* __restrict__ x, const float* __restrict__ w,
    __half* __restrict__ uhat)
{
    __shared__ float xl[16 * 640];  // [b][i] rows of 8 floats, stride 10 (40 KB)
    const int t  = threadIdx.x;
    const int i0 = blockIdx.x * 64;
    const int b0 = blockIdx.y * 16;
    const int j  = blockIdx.z;

    // stage x[b0:16][i0:64][8]: 2048 16B half-rows, lane-consecutive = coalesced
    #pragma unroll
    for (int c = 0; c < 8; ++c) {
        const int h  = t + 256 * c;        // 0..2047
        const int bb = h >> 7;
        const int ii = (h >> 1) & 63;
        const int nh = h & 1;
        const float4 xv4 = *(const float4*)(
            x + ((size_t)(b0 + bb) * NI + (i0 + ii)) * ID + nh * 4);
        float* dst = &xl[bb * 640 + ii * 10 + nh * 4];
        dst[0] = xv4.x; dst[1] = xv4.y; dst[2] = xv4.z; dst[3] = xv4.w;
    }

    const int lane = t & 63;
    const int il   = (t >> 6) * 16 + (lane >> 2);  // local i (0..63)
    const int i    = i0 + il;
    const int mq   = lane & 3;                     // m-quarter

    // w[i][j][n][mq*4..+4] for n=0..7: per instr, 4-lane groups read 64B contig
    const float* wp = w + ((size_t)i * NJ + j) * (ID * OD) + mq * 4;
    float wr[8][4];
    #pragma unroll
    for (int n = 0; n < 8; ++n)
        *(float4*)wr[n] = *(const float4*)(wp + n * OD);

    __syncthreads();

    for (int bb = 0; bb < 16; ++bb) {
        const float* xr = &xl[bb * 640 + il * 10];
        float xv[ID];
        #pragma unroll
        for (int q = 0; q < 4; ++q) { xv[2*q] = xr[2*q]; xv[2*q+1] = xr[2*q+1]; }
        float a0 = 0.f, a1 = 0.f, a2 = 0.f, a3 = 0.f;
        #pragma unroll
        for (int n = 0; n < ID; ++n) {
            a0 = fmaf(xv[n], wr[n][0], a0);
            a1 = fmaf(xv[n], wr[n][1], a1);
            a2 = fmaf(xv[n], wr[n][2], a2);
            a3 = fmaf(xv[n], wr[n][3], a3);
        }
        __half2 h01 = __floats2half2_rn(a0, a1);
        __half2 h23 = __floats2half2_rn(a2, a3);
        uint2 st;
        st.x = *(unsigned int*)&h01;
        st.y = *(unsigned int*)&h23;
        __half* up = uhat + (((size_t)(b0 + bb) * NJ + j) * NI + i) * OD + mq * 4;
        *(uint2*)up = st;  // wave: 16 i x 32B = 512B contiguous
    }
}

// ---------------- Routing core (DPP reduction) ----------------
#define P2T 192
#define P2I 6

template<int NT, int IPTT>
__device__ __forceinline__ void route_core(float (&u)[IPTT][OD], int t, int b, int j,
                                           float* __restrict__ out)
{
    constexpr int NW = NT / 64;
    __shared__ float4 red4[NW][5];
    const int wavei = t >> 6;
    const int lane  = t & 63;

    float logit[IPTT];
    #pragma unroll
    for (int k = 0; k < IPTT; ++k) logit[k] = 0.0f;
    float v[OD];

    for (int iter = 0; iter < 3; ++iter) {
        // deferred-normalization softmax accumulators
        float acc[OD + 1];
        #pragma unroll
        for (int q = 0; q <= OD; ++q) acc[q] = 0.0f;
        #pragma unroll
        for (int k = 0; k < IPTT; ++k) {
            const float c = __expf(logit[k]);
            acc[OD] += c;
            #pragma unroll
            for (int m = 0; m < OD; ++m) acc[m] = fmaf(c, u[k][m], acc[m]);
        }
        // 17 wave sums, pure VALU (no LDS pipe)
        #pragma unroll
        for (int q = 0; q <= OD; ++q) acc[q] = wave_sum63(acc[q]);

        if (iter != 0) __syncthreads();   // prev-iter red4 reads complete
        if (lane == 63) {
            red4[wavei][0] = make_float4(acc[0],  acc[1],  acc[2],  acc[3]);
            red4[wavei][1] = make_float4(acc[4],  acc[5],  acc[6],  acc[7]);
            red4[wavei][2] = make_float4(acc[8],  acc[9],  acc[10], acc[11]);
            red4[wavei][3] = make_float4(acc[12], acc[13], acc[14], acc[15]);
            red4[wavei][4] = make_float4(acc[16], 0.f, 0.f, 0.f);
        }
        __syncthreads();

        float tot[OD + 1];
        #pragma unroll
        for (int g = 0; g < 5; ++g) {
            float4 sum = red4[0][g];
            #pragma unroll
            for (int wv = 1; wv < NW; ++wv) {
                float4 r = red4[wv][g];
                sum.x += r.x; sum.y += r.y; sum.z += r.z; sum.w += r.w;
            }
            if (g < 4) {
                tot[4*g+0] = sum.x; tot[4*g+1] = sum.y;
                tot[4*g+2] = sum.z; tot[4*g+3] = sum.w;
            } else {
                tot[OD] = sum.x;
            }
        }

        const float inv_den = 1.0f / tot[OD];
        float s2 = 0.0f;
        float sv[OD];
        #pragma unroll
        for (int m = 0; m < OD; ++m) {
            sv[m] = tot[m] * inv_den;
            s2 = fmaf(sv[m], sv[m], s2);
        }
        const float scale = (s2 / (1.0f + s2)) / sqrtf(s2 + 1e-8f);
        #pragma unroll
        for (int m = 0; m < OD; ++m) v[m] = scale * sv[m];

        if (iter < 2) {
            #pragma unroll
            for (int k = 0; k < IPTT; ++k) {
                float a = 0.0f;
                #pragma unroll
                for (int m = 0; m < OD; ++m) a = fmaf(v[m], u[k][m], a);
                logit[k] += a;
            }
        }
    }
    if (t < OD) out[((size_t)b * NJ + j) * OD + t] = v[t];
}

// ---------------- Phase 2: stream u_hat, route ----------------
__global__ __launch_bounds__(P2T) void route_kernel(
    const __half* __restrict__ uhat, float* __restrict__ out)
{
    const int t = threadIdx.x;
    const int b = blockIdx.x & (NB - 1);
    const int j = blockIdx.x >> 7;

    const __half* upb = uhat + ((size_t)b * NJ + j) * NI * OD;
    float u[P2I][OD];
    #pragma unroll
    for (int k = 0; k < P2I; ++k) {
        const __half* p = upb + (size_t)(t + k * P2T) * OD;
        __half2 hp[8];
        *(float4*)&hp[0] = *(const float4*)(p);
        *(float4*)&hp[4] = *(const float4*)(p + 8);
        #pragma unroll
        for (int q = 0; q < 8; ++q) {
            float2 f = __half22float2(hp[q]);
            u[k][2*q] = f.x; u[k][2*q+1] = f.y;
        }
    }
    route_core<P2T, P2I>(u, t, b, j, out);
}

// ---------------- Fallback: fully fused fp32 (if d_ws too small) ----------------
__global__ __launch_bounds__(P2T) void fused_kernel(
    const float* __restrict__ x, const float* __restrict__ w,
    float* __restrict__ out)
{
    const int t = threadIdx.x;
    const int b = blockIdx.x & (NB - 1);
    const int j = blockIdx.x >> 7;

    float u[P2I][OD];
    #pragma unroll
    for (int k = 0; k < P2I; ++k) {
        const int i = t + k * P2T;
        const float* xp = x + ((size_t)b * NI + i) * ID;
        float xv[ID];
        const float4 x0 = *(const float4*)(xp);
        const float4 x1 = *(const float4*)(xp + 4);
        xv[0]=x0.x; xv[1]=x0.y; xv[2]=x0.z; xv[3]=x0.w;
        xv[4]=x1.x; xv[5]=x1.y; xv[6]=x1.z; xv[7]=x1.w;
        const float* wp = w + ((size_t)i * NJ + j) * (ID * OD);
        #pragma unroll
        for (int m = 0; m < OD; ++m) u[k][m] = 0.0f;
        #pragma unroll
        for (int n = 0; n < ID; ++n) {
            float wrow[OD];
            *(float4*)(wrow + 0)  = *(const float4*)(wp + n * OD + 0);
            *(float4*)(wrow + 4)  = *(const float4*)(wp + n * OD + 4);
            *(float4*)(wrow + 8)  = *(const float4*)(wp + n * OD + 8);
            *(float4*)(wrow + 12) = *(const float4*)(wp + n * OD + 12);
            const float xn = xv[n];
            #pragma unroll
            for (int m = 0; m < OD; ++m) u[k][m] = fmaf(xn, wrow[m], u[k][m]);
        }
    }
    route_core<P2T, P2I>(u, t, b, j, out);
}

extern "C" void kernel_launch(void* const* d_in, const int* in_sizes, int n_in,
                              void* d_out, int out_size, void* d_ws, size_t ws_size,
                              hipStream_t stream) {
    const float* x = (const float*)d_in[2];
    const float* w = (const float*)d_in[3];
    float* out = (float*)d_out;

    const size_t UHAT_BYTES = (size_t)NB * NJ * NI * OD * sizeof(__half); // ~47.2 MB

    if (ws_size >= UHAT_BYTES) {
        __half* uhat = (__half*)d_ws;
        hipLaunchKernelGGL(uhat_kernel, dim3(NI / 64, NB / 16, NJ), dim3(256),
                           0, stream, x, w, uhat);
        hipLaunchKernelGGL(route_kernel, dim3(NB * NJ), dim3(P2T),
                           0, stream, uhat, out);
    } else {
        hipLaunchKernelGGL(fused_kernel, dim3(NB * NJ), dim3(P2T),
                           0, stream, x, w, out);
    }
}